// Round 4
// baseline (516.379 us; speedup 1.0000x reference)
//
#include <hip/hip_runtime.h>
#include <hip/hip_bf16.h>

#define IN_FEATS 768

typedef __attribute__((ext_vector_type(8))) short short8v;
typedef __attribute__((ext_vector_type(4))) float f32x4;

__device__ __forceinline__ unsigned short f2bf(float f) {
    union { float f; unsigned int u; } c; c.f = f;
    unsigned int r = (c.u + 0x7FFFu + ((c.u >> 16) & 1u)) >> 16;  // RNE
    return (unsigned short)r;
}
__device__ __forceinline__ float bflo(unsigned int v) {
    union { unsigned int u; float f; } c; c.u = v << 16; return c.f;
}
__device__ __forceinline__ float bfhi(unsigned int v) {
    union { unsigned int u; float f; } c; c.u = v & 0xFFFF0000u; return c.f;
}

// ---------------------------------------------------------------------------
// Kernel 0: zero the count buffer (replaces hipMemsetAsync — graph-captured
// rocclr fill nodes measured ~175 us each regardless of size; this is ~2 us).
// ---------------------------------------------------------------------------
__global__ __launch_bounds__(256) void zero_cnt_kernel(int* __restrict__ cnt, int N)
{
    const int i = blockIdx.x * blockDim.x + threadIdx.x;
    if (i < N) cnt[i] = 0;
}

// ---------------------------------------------------------------------------
// Kernel 1: fused layer-1 linear via bf16 MFMA.
// hn1b = bf16(x @ Wn1.T)  [N,32] ; hs1 = x @ Ws1.T + b1 (fp32) [N,32]
// BM=64, BN=64 (cols 0-31: Wn, 32-63: Ws), BK=32, 4 waves, 16x16x32 MFMA.
// ---------------------------------------------------------------------------
__global__ __launch_bounds__(256) void gemm1_kernel(
    const float* __restrict__ x,
    const float* __restrict__ Wn,
    const float* __restrict__ Ws,
    const float* __restrict__ b1,
    unsigned short* __restrict__ hn1b,   // [N,32] bf16 bits
    float* __restrict__ hs1,             // [N,32]
    int N)
{
    __shared__ unsigned short As[64][32];   // [row][k] bf16
    __shared__ unsigned short Bs[64][32];   // [outcol][k] bf16

    const int tid  = threadIdx.x;
    const int lrow = tid >> 2;          // 0..63
    const int lk8  = (tid & 3) * 8;     // 0,8,16,24
    const int row0 = blockIdx.x * 64;

    const int  grow   = row0 + lrow;
    const bool rvalid = (grow < N);
    const float* xrow = x + (size_t)(rvalid ? grow : (N - 1)) * IN_FEATS;
    const float* wrow = (lrow < 32) ? (Wn + (size_t)lrow * IN_FEATS)
                                    : (Ws + (size_t)(lrow - 32) * IN_FEATS);

    const int w    = tid >> 6;          // wave 0..3
    const int l    = tid & 63;
    const int lr16 = l & 15;
    const int lk   = (l >> 4) * 8;

    f32x4 acc[4];
#pragma unroll
    for (int ct = 0; ct < 4; ++ct) acc[ct] = (f32x4){0.f, 0.f, 0.f, 0.f};

    // prologue loads (k0 = 0)
    float4 a0 = *(const float4*)(xrow + lk8);
    float4 a1 = *(const float4*)(xrow + lk8 + 4);
    float4 w0 = *(const float4*)(wrow + lk8);
    float4 w1 = *(const float4*)(wrow + lk8 + 4);

    for (int step = 0; step < IN_FEATS / 32; ++step) {
        // convert + stage current K-slab
        unsigned short* ap = &As[lrow][lk8];
        ap[0] = f2bf(a0.x); ap[1] = f2bf(a0.y); ap[2] = f2bf(a0.z); ap[3] = f2bf(a0.w);
        ap[4] = f2bf(a1.x); ap[5] = f2bf(a1.y); ap[6] = f2bf(a1.z); ap[7] = f2bf(a1.w);
        unsigned short* bp = &Bs[lrow][lk8];
        bp[0] = f2bf(w0.x); bp[1] = f2bf(w0.y); bp[2] = f2bf(w0.z); bp[3] = f2bf(w0.w);
        bp[4] = f2bf(w1.x); bp[5] = f2bf(w1.y); bp[6] = f2bf(w1.z); bp[7] = f2bf(w1.w);
        __syncthreads();

        // issue next slab's global loads (overlap with MFMA section)
        if (step + 1 < IN_FEATS / 32) {
            const int k0 = (step + 1) * 32;
            a0 = *(const float4*)(xrow + k0 + lk8);
            a1 = *(const float4*)(xrow + k0 + lk8 + 4);
            w0 = *(const float4*)(wrow + k0 + lk8);
            w1 = *(const float4*)(wrow + k0 + lk8 + 4);
        }

        short8v afrag = *(const short8v*)&As[w * 16 + lr16][lk];
#pragma unroll
        for (int ct = 0; ct < 4; ++ct) {
            short8v bfrag = *(const short8v*)&Bs[ct * 16 + lr16][lk];
            acc[ct] = __builtin_amdgcn_mfma_f32_16x16x32_bf16(afrag, bfrag, acc[ct], 0, 0, 0);
        }
        __syncthreads();
    }

    // epilogue: D layout col=lane&15, row=(lane>>4)*4+reg
    const int rbase = row0 + w * 16 + (l >> 4) * 4;
#pragma unroll
    for (int ct = 0; ct < 4; ++ct) {
        const int ncol = ct * 16 + lr16;
        if (ncol < 32) {
#pragma unroll
            for (int j = 0; j < 4; ++j) {
                const int r = rbase + j;
                if (r < N) hn1b[(size_t)r * 32 + ncol] = f2bf(acc[ct][j]);
            }
        } else {
            const int c = ncol - 32;
            const float bias = b1[c];
#pragma unroll
            for (int j = 0; j < 4; ++j) {
                const int r = rbase + j;
                if (r < N) hs1[(size_t)r * 32 + c] = acc[ct][j] + bias;
            }
        }
    }
}

// ---------------------------------------------------------------------------
// CSR construction: histogram -> exclusive scan -> scatter
// ---------------------------------------------------------------------------
__global__ __launch_bounds__(256) void hist_kernel(
    const int* __restrict__ dst, int* __restrict__ cnt, int E)
{
    const int e = blockIdx.x * blockDim.x + threadIdx.x;
    if (e < E) atomicAdd(&cnt[dst[e]], 1);
}

__global__ __launch_bounds__(256) void scan_part_kernel(
    const int* __restrict__ cnt, int* __restrict__ partial, int N)
{
    __shared__ int sdata[256];
    const int t = threadIdx.x;
    const int base = blockIdx.x * 1024 + t * 4;
    int s = 0;
#pragma unroll
    for (int k = 0; k < 4; ++k) {
        const int i = base + k;
        if (i < N) s += cnt[i];
    }
    sdata[t] = s;
    __syncthreads();
    for (int off = 128; off > 0; off >>= 1) {
        if (t < off) sdata[t] += sdata[t + off];
        __syncthreads();
    }
    if (t == 0) partial[blockIdx.x] = sdata[0];
}

__global__ void scan_mid_kernel(int* __restrict__ partial, int nb)
{
    if (threadIdx.x == 0 && blockIdx.x == 0) {
        int run = 0;
        for (int b = 0; b < nb; ++b) {
            const int v = partial[b];
            partial[b] = run;
            run += v;
        }
    }
}

// Writes rowstart[i] (exclusive prefix) AND initializes cursor[i] = rowstart[i]
// (cursor aliases cnt: each i is read then written by exactly one thread).
__global__ __launch_bounds__(256) void scan_write_kernel(
    const int* __restrict__ cnt, const int* __restrict__ partial,
    int* __restrict__ rowstart, int* __restrict__ cursor, int N, int E)
{
    __shared__ int sdata[256];
    const int t = threadIdx.x;
    const int base = blockIdx.x * 1024 + t * 4;
    int v[4];
    int s = 0;
#pragma unroll
    for (int k = 0; k < 4; ++k) {
        const int i = base + k;
        v[k] = (i < N) ? cnt[i] : 0;
        s += v[k];
    }
    sdata[t] = s;
    __syncthreads();
    for (int off = 1; off < 256; off <<= 1) {
        const int add = (t >= off) ? sdata[t - off] : 0;
        __syncthreads();
        sdata[t] += add;
        __syncthreads();
    }
    int excl = (t > 0 ? sdata[t - 1] : 0) + partial[blockIdx.x];
#pragma unroll
    for (int k = 0; k < 4; ++k) {
        const int i = base + k;
        if (i < N) { rowstart[i] = excl; cursor[i] = excl; excl += v[k]; }
    }
    if (blockIdx.x == 0 && t == 0) rowstart[N] = E;
}

__global__ __launch_bounds__(256) void scatter_kernel(
    const int* __restrict__ src, const int* __restrict__ dst,
    int* __restrict__ cursor, int* __restrict__ edge_src, int E)
{
    const int e = blockIdx.x * blockDim.x + threadIdx.x;
    if (e >= E) return;
    const int d = dst[e];
    const int p = atomicAdd(&cursor[d], 1);   // absolute position
    edge_src[p] = src[e];
}

// ---------------------------------------------------------------------------
// agg1 fused: 16 nodes/block, 16 lanes/node, bf16x2 gathers from hn1b.
// h = relu(hs1 + mean(gather)) ; hn2b = bf16(h @ Wn2.T) ; hs2 = h @ Ws2.T + b2
// ---------------------------------------------------------------------------
__global__ __launch_bounds__(256) void agg1_fused_kernel(
    const unsigned short* __restrict__ hn1b, const float* __restrict__ hs1,
    const int* __restrict__ rowstart, const int* __restrict__ edge_src,
    const float* __restrict__ Wn2,   // [8,32]
    const float* __restrict__ Ws2,   // [8,32]
    const float* __restrict__ b2,    // [8]
    unsigned short* __restrict__ hn2b,  // [N,8] bf16 bits
    float* __restrict__ hs2,            // [N,8]
    int N)
{
    __shared__ float w2[16][33];     // rows 0..7 Wn2, 8..15 Ws2 (+1 pad)
    __shared__ float bb[8];
    __shared__ float hsm[16][33];

    const int tid = threadIdx.x;
    const int g   = tid >> 4;        // node slot 0..15
    const int ln  = tid & 15;        // feature-pair lane

    w2[tid >> 5][tid & 31]       = Wn2[tid];
    w2[8 + (tid >> 5)][tid & 31] = Ws2[tid];
    if (tid < 8) bb[tid] = b2[tid];

    const unsigned int* hn1u = (const unsigned int*)hn1b;  // [N][16] packed pairs

    const int n = blockIdx.x * 16 + g;
    float sx = 0.f, sy = 0.f;
    int degi = 0;
    if (n < N) {
        const int rs = rowstart[n];
        const int re = rowstart[n + 1];
        degi = re - rs;
        int e = rs;
        for (; e + 4 <= re; e += 4) {
            const int s0 = edge_src[e + 0];
            const int s1 = edge_src[e + 1];
            const int s2 = edge_src[e + 2];
            const int s3 = edge_src[e + 3];
            const unsigned int v0 = hn1u[(size_t)s0 * 16 + ln];
            const unsigned int v1 = hn1u[(size_t)s1 * 16 + ln];
            const unsigned int v2 = hn1u[(size_t)s2 * 16 + ln];
            const unsigned int v3 = hn1u[(size_t)s3 * 16 + ln];
            sx += (bflo(v0) + bflo(v1)) + (bflo(v2) + bflo(v3));
            sy += (bfhi(v0) + bfhi(v1)) + (bfhi(v2) + bfhi(v3));
        }
        for (; e < re; ++e) {
            const unsigned int v = hn1u[(size_t)edge_src[e] * 16 + ln];
            sx += bflo(v); sy += bfhi(v);
        }
        const float inv = 1.0f / fmaxf((float)degi, 1.0f);
        const float2 hs = *(const float2*)(hs1 + (size_t)n * 32 + 2 * ln);
        hsm[g][2 * ln + 0] = fmaxf(hs.x + sx * inv, 0.0f);
        hsm[g][2 * ln + 1] = fmaxf(hs.y + sy * inv, 0.0f);
    }
    __syncthreads();

    // layer-2 linears: 16 lanes per node -> 16 outputs (8 hn2 + 8 hs2)
    if (n < N) {
        const float* wrow = w2[ln];
        const float* hv   = hsm[g];
        float acc = 0.0f;
#pragma unroll
        for (int k = 0; k < 32; ++k) acc += wrow[k] * hv[k];
        if (ln < 8) hn2b[(size_t)n * 8 + ln] = f2bf(acc);
        else        hs2[(size_t)n * 8 + (ln - 8)] = acc + bb[ln - 8];
    }
}

// ---------------------------------------------------------------------------
// agg2 fused: 16 nodes/block; per node 4 edge-slots x 4 feat-pair lanes.
// out = hs2 + mean(gather hn2b)
// ---------------------------------------------------------------------------
__global__ __launch_bounds__(256) void agg2_fused_kernel(
    const unsigned short* __restrict__ hn2b, const float* __restrict__ hs2,
    const int* __restrict__ rowstart, const int* __restrict__ edge_src,
    float* __restrict__ out, int N)
{
    const int tid  = threadIdx.x;
    const int g    = tid >> 4;       // node slot 0..15
    const int ln   = tid & 15;
    const int slot = ln >> 2;        // 0..3
    const int q    = ln & 3;         // feature pair 0..3

    const unsigned int* hn2u = (const unsigned int*)hn2b;  // [N][4]

    const int n = blockIdx.x * 16 + g;
    float sx = 0.f, sy = 0.f;
    int degi = 0;
    if (n < N) {
        const int rs = rowstart[n];
        const int re = rowstart[n + 1];
        degi = re - rs;
        for (int e = rs + slot; e < re; e += 4) {
            const unsigned int v = hn2u[(size_t)edge_src[e] * 4 + q];
            sx += bflo(v); sy += bfhi(v);
        }
    }
    // reduce the 4 slots: lanes q, q+4, q+8, q+12 within the 16-lane group
    sx += __shfl_xor(sx, 4, 64);  sy += __shfl_xor(sy, 4, 64);
    sx += __shfl_xor(sx, 8, 64);  sy += __shfl_xor(sy, 8, 64);

    if (n < N && slot == 0) {
        const float inv = 1.0f / fmaxf((float)degi, 1.0f);
        const float2 s = *(const float2*)(hs2 + (size_t)n * 8 + 2 * q);
        float2 o;
        o.x = s.x + sx * inv;
        o.y = s.y + sy * inv;
        *(float2*)(out + (size_t)n * 8 + 2 * q) = o;
    }
}

extern "C" void kernel_launch(void* const* d_in, const int* in_sizes, int n_in,
                              void* d_out, int out_size, void* d_ws, size_t ws_size,
                              hipStream_t stream)
{
    const float* feats = (const float*)d_in[0];
    const int*   src   = (const int*)d_in[1];
    const int*   dst   = (const int*)d_in[2];
    const float* Ws1   = (const float*)d_in[3];
    const float* Wn1   = (const float*)d_in[4];
    const float* b1    = (const float*)d_in[5];
    const float* Ws2   = (const float*)d_in[6];
    const float* Wn2   = (const float*)d_in[7];
    const float* b2    = (const float*)d_in[8];
    float* out = (float*)d_out;

    const int N = in_sizes[0] / IN_FEATS;   // 100000
    const int E = in_sizes[1];              // 3200000

    // Workspace layout
    char* ws = (char*)d_ws;
    const size_t N32 = (size_t)N * 32;
    const size_t N8  = (size_t)N * 8;
    unsigned short* hn1b = (unsigned short*)ws;            // [N,32] bf16
    ws += ((N32 * 2 + 255) / 256) * 256;
    float* hs1 = (float*)ws;                               // [N,32] f32
    ws += ((N32 * 4 + 255) / 256) * 256;
    unsigned short* hn2b = (unsigned short*)ws;            // [N,8] bf16
    ws += ((N8 * 2 + 255) / 256) * 256;
    float* hs2 = (float*)ws;                               // [N,8] f32
    ws += ((N8 * 4 + 255) / 256) * 256;
    int* rowstart = (int*)ws;                              // [N+1]
    ws += (((size_t)(N + 1) * 4 + 255) / 256) * 256;
    int* cnt = (int*)ws;                                   // [N] (doubles as cursor)
    ws += (((size_t)N * 4 + 255) / 256) * 256;
    int* partial = (int*)ws;                               // [128]
    ws += 128 * 4;
    int* edge_src = (int*)ws;                              // [E]

    const int nbScan = (N + 1023) / 1024;

    // --- CSR build (no hipMemsetAsync anywhere: graph-captured fill nodes
    //     measured ~175 us each regardless of size) ---
    zero_cnt_kernel<<<(N + 255) / 256, 256, 0, stream>>>(cnt, N);
    hist_kernel<<<(E + 255) / 256, 256, 0, stream>>>(dst, cnt, E);
    scan_part_kernel<<<nbScan, 256, 0, stream>>>(cnt, partial, N);
    scan_mid_kernel<<<1, 64, 0, stream>>>(partial, nbScan);
    scan_write_kernel<<<nbScan, 256, 0, stream>>>(cnt, partial, rowstart, cnt, N, E);
    scatter_kernel<<<(E + 255) / 256, 256, 0, stream>>>(src, dst, cnt, edge_src, E);

    // --- layer-1 fused GEMM (bf16 MFMA) ---
    gemm1_kernel<<<(N + 63) / 64, 256, 0, stream>>>(feats, Wn1, Ws1, b1,
                                                    hn1b, hs1, N);

    // --- layer-1 aggregation + finish + layer-2 linear ---
    agg1_fused_kernel<<<(N + 15) / 16, 256, 0, stream>>>(
        hn1b, hs1, rowstart, edge_src, Wn2, Ws2, b2, hn2b, hs2, N);

    // --- layer-2 aggregation + final combine ---
    agg2_fused_kernel<<<(N + 15) / 16, 256, 0, stream>>>(
        hn2b, hs2, rowstart, edge_src, out, N);
}

// Round 5
// 271.096 us; speedup vs baseline: 1.9048x; 1.9048x over previous
//
#include <hip/hip_runtime.h>
#include <hip/hip_bf16.h>

#define IN_FEATS 768
#define PART_CHUNK 8192
#define SRC_BITS 17
#define SRC_MASK 0x1FFFF

typedef __attribute__((ext_vector_type(8))) short short8v;
typedef __attribute__((ext_vector_type(4))) float f32x4;

__device__ __forceinline__ unsigned short f2bf(float f) {
    union { float f; unsigned int u; } c; c.f = f;
    unsigned int r = (c.u + 0x7FFFu + ((c.u >> 16) & 1u)) >> 16;  // RNE
    return (unsigned short)r;
}
__device__ __forceinline__ float bflo(unsigned int v) {
    union { unsigned int u; float f; } c; c.u = v << 16; return c.f;
}
__device__ __forceinline__ float bfhi(unsigned int v) {
    union { unsigned int u; float f; } c; c.u = v & 0xFFFF0000u; return c.f;
}

// ---------------------------------------------------------------------------
// Kernel 1: fused layer-1 linear via bf16 MFMA (unchanged).
// ---------------------------------------------------------------------------
__global__ __launch_bounds__(256) void gemm1_kernel(
    const float* __restrict__ x,
    const float* __restrict__ Wn,
    const float* __restrict__ Ws,
    const float* __restrict__ b1,
    unsigned short* __restrict__ hn1b,   // [N,32] bf16 bits
    float* __restrict__ hs1,             // [N,32]
    int N)
{
    __shared__ unsigned short As[64][32];
    __shared__ unsigned short Bs[64][32];

    const int tid  = threadIdx.x;
    const int lrow = tid >> 2;
    const int lk8  = (tid & 3) * 8;
    const int row0 = blockIdx.x * 64;

    const int  grow   = row0 + lrow;
    const bool rvalid = (grow < N);
    const float* xrow = x + (size_t)(rvalid ? grow : (N - 1)) * IN_FEATS;
    const float* wrow = (lrow < 32) ? (Wn + (size_t)lrow * IN_FEATS)
                                    : (Ws + (size_t)(lrow - 32) * IN_FEATS);

    const int w    = tid >> 6;
    const int l    = tid & 63;
    const int lr16 = l & 15;
    const int lk   = (l >> 4) * 8;

    f32x4 acc[4];
#pragma unroll
    for (int ct = 0; ct < 4; ++ct) acc[ct] = (f32x4){0.f, 0.f, 0.f, 0.f};

    float4 a0 = *(const float4*)(xrow + lk8);
    float4 a1 = *(const float4*)(xrow + lk8 + 4);
    float4 w0 = *(const float4*)(wrow + lk8);
    float4 w1 = *(const float4*)(wrow + lk8 + 4);

    for (int step = 0; step < IN_FEATS / 32; ++step) {
        unsigned short* ap = &As[lrow][lk8];
        ap[0] = f2bf(a0.x); ap[1] = f2bf(a0.y); ap[2] = f2bf(a0.z); ap[3] = f2bf(a0.w);
        ap[4] = f2bf(a1.x); ap[5] = f2bf(a1.y); ap[6] = f2bf(a1.z); ap[7] = f2bf(a1.w);
        unsigned short* bp = &Bs[lrow][lk8];
        bp[0] = f2bf(w0.x); bp[1] = f2bf(w0.y); bp[2] = f2bf(w0.z); bp[3] = f2bf(w0.w);
        bp[4] = f2bf(w1.x); bp[5] = f2bf(w1.y); bp[6] = f2bf(w1.z); bp[7] = f2bf(w1.w);
        __syncthreads();

        if (step + 1 < IN_FEATS / 32) {
            const int k0 = (step + 1) * 32;
            a0 = *(const float4*)(xrow + k0 + lk8);
            a1 = *(const float4*)(xrow + k0 + lk8 + 4);
            w0 = *(const float4*)(wrow + k0 + lk8);
            w1 = *(const float4*)(wrow + k0 + lk8 + 4);
        }

        short8v afrag = *(const short8v*)&As[w * 16 + lr16][lk];
#pragma unroll
        for (int ct = 0; ct < 4; ++ct) {
            short8v bfrag = *(const short8v*)&Bs[ct * 16 + lr16][lk];
            acc[ct] = __builtin_amdgcn_mfma_f32_16x16x32_bf16(afrag, bfrag, acc[ct], 0, 0, 0);
        }
        __syncthreads();
    }

    const int rbase = row0 + w * 16 + (l >> 4) * 4;
#pragma unroll
    for (int ct = 0; ct < 4; ++ct) {
        const int ncol = ct * 16 + lr16;
        if (ncol < 32) {
#pragma unroll
            for (int j = 0; j < 4; ++j) {
                const int r = rbase + j;
                if (r < N) hn1b[(size_t)r * 32 + ncol] = f2bf(acc[ct][j]);
            }
        } else {
            const int c = ncol - 32;
            const float bias = b1[c];
#pragma unroll
            for (int j = 0; j < 4; ++j) {
                const int r = rbase + j;
                if (r < N) hs1[(size_t)r * 32 + c] = acc[ct][j] + bias;
            }
        }
    }
}

// ---------------------------------------------------------------------------
// CSR build, locality-aware. Buckets of 256 nodes: b = dst >> 8, NB = ceil(N/256).
// ---------------------------------------------------------------------------
__global__ __launch_bounds__(512) void zero_bcnt_kernel(int* __restrict__ bcnt, int NB)
{
    const int t = threadIdx.x;
    if (t < NB) bcnt[t] = 0;
}

__global__ __launch_bounds__(256) void bucket_hist_kernel(
    const int* __restrict__ dst, int* __restrict__ bcnt, int NB, int E)
{
    __shared__ int h[512];
    const int t = threadIdx.x;
    for (int i = t; i < NB; i += 256) h[i] = 0;
    __syncthreads();
    const int start = blockIdx.x * PART_CHUNK;
    const int end = min(start + PART_CHUNK, E);
    for (int i = start + t; i < end; i += 256)
        atomicAdd(&h[dst[i] >> 8], 1);
    __syncthreads();
    for (int i = t; i < NB; i += 256)
        if (h[i]) atomicAdd(&bcnt[i], h[i]);
}

// single block, 512 threads: exclusive scan of bcnt -> bstart[NB+1]; bcursor = bstart
__global__ __launch_bounds__(512) void bucket_scan_kernel(
    const int* __restrict__ bcnt, int* __restrict__ bstart,
    int* __restrict__ bcursor, int NB, int E)
{
    __shared__ int s[512];
    const int t = threadIdx.x;
    s[t] = (t < NB) ? bcnt[t] : 0;
    __syncthreads();
    for (int off = 1; off < 512; off <<= 1) {
        const int add = (t >= off) ? s[t - off] : 0;
        __syncthreads();
        s[t] += add;
        __syncthreads();
    }
    const int excl = (t > 0) ? s[t - 1] : 0;
    if (t < NB) { bstart[t] = excl; bcursor[t] = excl; }
    if (t == 0) bstart[NB] = E;
}

// partition: per-block LDS histogram + one run-reservation atomic per bucket,
// then packed writes ((dst&255)<<17 | src) into the block's contiguous runs.
__global__ __launch_bounds__(256) void partition_kernel(
    const int* __restrict__ src, const int* __restrict__ dst,
    int* __restrict__ bcursor, unsigned int* __restrict__ packed,
    int NB, int E)
{
    __shared__ int hcnt[512];
    __shared__ int hbase[512];
    const int t = threadIdx.x;
    for (int i = t; i < NB; i += 256) hcnt[i] = 0;
    __syncthreads();
    const int start = blockIdx.x * PART_CHUNK;
    const int end = min(start + PART_CHUNK, E);
    for (int i = start + t; i < end; i += 256)
        atomicAdd(&hcnt[dst[i] >> 8], 1);
    __syncthreads();
    for (int i = t; i < NB; i += 256) {
        const int c = hcnt[i];
        hbase[i] = c ? atomicAdd(&bcursor[i], c) : 0;
        hcnt[i] = 0;   // reuse as local cursor
    }
    __syncthreads();
    for (int i = start + t; i < end; i += 256) {
        const int d = dst[i];
        const int b = d >> 8;
        const int p = hbase[b] + atomicAdd(&hcnt[b], 1);
        packed[p] = ((unsigned int)(d & 255) << SRC_BITS) | (unsigned int)src[i];
    }
}

// per-bucket CSR finalize: per-node counts -> rowstart, then in-window scatter.
// All scattered writes land in this bucket's ~32 KB edge_src window (one block
// -> one XCD L2 -> single writeback per line).
__global__ __launch_bounds__(256) void csr_finalize_kernel(
    const unsigned int* __restrict__ packed, const int* __restrict__ bstart,
    int* __restrict__ rowstart, int* __restrict__ edge_src,
    int NB, int N, int E)
{
    __shared__ int cnt[256];
    __shared__ int sdata[256];
    __shared__ int cur[256];
    const int b = blockIdx.x;
    const int t = threadIdx.x;
    const int base = bstart[b];
    const int endp = bstart[b + 1];

    cnt[t] = 0;
    __syncthreads();
    for (int i = base + t; i < endp; i += 256)
        atomicAdd(&cnt[packed[i] >> SRC_BITS], 1);
    __syncthreads();

    sdata[t] = cnt[t];
    __syncthreads();
    for (int off = 1; off < 256; off <<= 1) {
        const int add = (t >= off) ? sdata[t - off] : 0;
        __syncthreads();
        sdata[t] += add;
        __syncthreads();
    }
    const int excl = (t > 0) ? sdata[t - 1] : 0;
    const int n = (b << 8) + t;
    if (n < N) rowstart[n] = base + excl;
    if (b == NB - 1 && t == 0) rowstart[N] = E;
    cur[t] = base + excl;
    __syncthreads();

    for (int i = base + t; i < endp; i += 256) {
        const unsigned int v = packed[i];
        const int pos = atomicAdd(&cur[v >> SRC_BITS], 1);
        edge_src[pos] = (int)(v & SRC_MASK);
    }
}

// ---------------------------------------------------------------------------
// agg1 fused (unchanged): 16 nodes/block, 16 lanes/node, bf16x2 gathers.
// ---------------------------------------------------------------------------
__global__ __launch_bounds__(256) void agg1_fused_kernel(
    const unsigned short* __restrict__ hn1b, const float* __restrict__ hs1,
    const int* __restrict__ rowstart, const int* __restrict__ edge_src,
    const float* __restrict__ Wn2, const float* __restrict__ Ws2,
    const float* __restrict__ b2,
    unsigned short* __restrict__ hn2b, float* __restrict__ hs2, int N)
{
    __shared__ float w2[16][33];
    __shared__ float bb[8];
    __shared__ float hsm[16][33];

    const int tid = threadIdx.x;
    const int g   = tid >> 4;
    const int ln  = tid & 15;

    w2[tid >> 5][tid & 31]       = Wn2[tid];
    w2[8 + (tid >> 5)][tid & 31] = Ws2[tid];
    if (tid < 8) bb[tid] = b2[tid];

    const unsigned int* hn1u = (const unsigned int*)hn1b;

    const int n = blockIdx.x * 16 + g;
    float sx = 0.f, sy = 0.f;
    int degi = 0;
    if (n < N) {
        const int rs = rowstart[n];
        const int re = rowstart[n + 1];
        degi = re - rs;
        int e = rs;
        for (; e + 4 <= re; e += 4) {
            const int s0 = edge_src[e + 0];
            const int s1 = edge_src[e + 1];
            const int s2 = edge_src[e + 2];
            const int s3 = edge_src[e + 3];
            const unsigned int v0 = hn1u[(size_t)s0 * 16 + ln];
            const unsigned int v1 = hn1u[(size_t)s1 * 16 + ln];
            const unsigned int v2 = hn1u[(size_t)s2 * 16 + ln];
            const unsigned int v3 = hn1u[(size_t)s3 * 16 + ln];
            sx += (bflo(v0) + bflo(v1)) + (bflo(v2) + bflo(v3));
            sy += (bfhi(v0) + bfhi(v1)) + (bfhi(v2) + bfhi(v3));
        }
        for (; e < re; ++e) {
            const unsigned int v = hn1u[(size_t)edge_src[e] * 16 + ln];
            sx += bflo(v); sy += bfhi(v);
        }
        const float inv = 1.0f / fmaxf((float)degi, 1.0f);
        const float2 hs = *(const float2*)(hs1 + (size_t)n * 32 + 2 * ln);
        hsm[g][2 * ln + 0] = fmaxf(hs.x + sx * inv, 0.0f);
        hsm[g][2 * ln + 1] = fmaxf(hs.y + sy * inv, 0.0f);
    }
    __syncthreads();

    if (n < N) {
        const float* wrow = w2[ln];
        const float* hv   = hsm[g];
        float acc = 0.0f;
#pragma unroll
        for (int k = 0; k < 32; ++k) acc += wrow[k] * hv[k];
        if (ln < 8) hn2b[(size_t)n * 8 + ln] = f2bf(acc);
        else        hs2[(size_t)n * 8 + (ln - 8)] = acc + bb[ln - 8];
    }
}

// ---------------------------------------------------------------------------
// agg2 fused (unchanged): out = hs2 + mean(gather hn2b)
// ---------------------------------------------------------------------------
__global__ __launch_bounds__(256) void agg2_fused_kernel(
    const unsigned short* __restrict__ hn2b, const float* __restrict__ hs2,
    const int* __restrict__ rowstart, const int* __restrict__ edge_src,
    float* __restrict__ out, int N)
{
    const int tid  = threadIdx.x;
    const int g    = tid >> 4;
    const int ln   = tid & 15;
    const int slot = ln >> 2;
    const int q    = ln & 3;

    const unsigned int* hn2u = (const unsigned int*)hn2b;

    const int n = blockIdx.x * 16 + g;
    float sx = 0.f, sy = 0.f;
    int degi = 0;
    if (n < N) {
        const int rs = rowstart[n];
        const int re = rowstart[n + 1];
        degi = re - rs;
        for (int e = rs + slot; e < re; e += 4) {
            const unsigned int v = hn2u[(size_t)edge_src[e] * 4 + q];
            sx += bflo(v); sy += bfhi(v);
        }
    }
    sx += __shfl_xor(sx, 4, 64);  sy += __shfl_xor(sy, 4, 64);
    sx += __shfl_xor(sx, 8, 64);  sy += __shfl_xor(sy, 8, 64);

    if (n < N && slot == 0) {
        const float inv = 1.0f / fmaxf((float)degi, 1.0f);
        const float2 s = *(const float2*)(hs2 + (size_t)n * 8 + 2 * q);
        float2 o;
        o.x = s.x + sx * inv;
        o.y = s.y + sy * inv;
        *(float2*)(out + (size_t)n * 8 + 2 * q) = o;
    }
}

extern "C" void kernel_launch(void* const* d_in, const int* in_sizes, int n_in,
                              void* d_out, int out_size, void* d_ws, size_t ws_size,
                              hipStream_t stream)
{
    const float* feats = (const float*)d_in[0];
    const int*   src   = (const int*)d_in[1];
    const int*   dst   = (const int*)d_in[2];
    const float* Ws1   = (const float*)d_in[3];
    const float* Wn1   = (const float*)d_in[4];
    const float* b1    = (const float*)d_in[5];
    const float* Ws2   = (const float*)d_in[6];
    const float* Wn2   = (const float*)d_in[7];
    const float* b2    = (const float*)d_in[8];
    float* out = (float*)d_out;

    const int N = in_sizes[0] / IN_FEATS;   // 100000
    const int E = in_sizes[1];              // 3200000
    const int NB = (N + 255) >> 8;          // 391 buckets of 256 nodes

    // Workspace layout
    char* ws = (char*)d_ws;
    const size_t N32 = (size_t)N * 32;
    const size_t N8  = (size_t)N * 8;
    unsigned short* hn1b = (unsigned short*)ws;            // [N,32] bf16
    ws += ((N32 * 2 + 255) / 256) * 256;
    float* hs1 = (float*)ws;                               // [N,32] f32
    ws += ((N32 * 4 + 255) / 256) * 256;
    unsigned short* hn2b = (unsigned short*)ws;            // [N,8] bf16
    ws += ((N8 * 2 + 255) / 256) * 256;
    float* hs2 = (float*)ws;                               // [N,8] f32
    ws += ((N8 * 4 + 255) / 256) * 256;
    int* rowstart = (int*)ws;                              // [N+1]
    ws += (((size_t)(N + 1) * 4 + 255) / 256) * 256;
    int* bcnt = (int*)ws;                                  // [NB]
    ws += 512 * 4;
    int* bstart = (int*)ws;                                // [NB+1]
    ws += 520 * 4;
    int* bcursor = (int*)ws;                               // [NB]
    ws += 512 * 4;
    unsigned int* packed = (unsigned int*)ws;              // [E]
    ws += (((size_t)E * 4 + 255) / 256) * 256;
    int* edge_src = (int*)ws;                              // [E]

    const int nbPart = (E + PART_CHUNK - 1) / PART_CHUNK;

    // --- CSR build (locality-aware two-level partition) ---
    zero_bcnt_kernel<<<1, 512, 0, stream>>>(bcnt, NB);
    bucket_hist_kernel<<<nbPart, 256, 0, stream>>>(dst, bcnt, NB, E);
    bucket_scan_kernel<<<1, 512, 0, stream>>>(bcnt, bstart, bcursor, NB, E);
    partition_kernel<<<nbPart, 256, 0, stream>>>(src, dst, bcursor, packed, NB, E);
    csr_finalize_kernel<<<NB, 256, 0, stream>>>(packed, bstart, rowstart,
                                                edge_src, NB, N, E);

    // --- layer-1 fused GEMM (bf16 MFMA) ---
    gemm1_kernel<<<(N + 63) / 64, 256, 0, stream>>>(feats, Wn1, Ws1, b1,
                                                    hn1b, hs1, N);

    // --- layer-1 aggregation + finish + layer-2 linear ---
    agg1_fused_kernel<<<(N + 15) / 16, 256, 0, stream>>>(
        hn1b, hs1, rowstart, edge_src, Wn2, Ws2, b2, hn2b, hs2, N);

    // --- layer-2 aggregation + final combine ---
    agg2_fused_kernel<<<(N + 15) / 16, 256, 0, stream>>>(
        hn2b, hs2, rowstart, edge_src, out, N);
}